// Round 7
// baseline (602.529 us; speedup 1.0000x reference)
//
#include <hip/hip_runtime.h>
#include <math.h>

#define Bb 256
#define Tt 1024
#define Ll 128

// ---------------- exp(trans) transpose precompute ----------------
// expT[j*128 + i] = exp(trans[i*128 + j])
__global__ __launch_bounds__(256) void crf_expT_kernel(
    const float* __restrict__ trans, float* __restrict__ expT)
{
    int idx = blockIdx.x * 256 + threadIdx.x;   // idx = j*128 + i
    if (idx < Ll * Ll) {
        int jj = idx >> 7;
        int ii = idx & (Ll - 1);
        expT[idx] = __expf(trans[ii * Ll + jj]);
    }
}

// ---------------- numerator kernel ----------------
__global__ __launch_bounds__(256) void crf_num_kernel(
    const float* __restrict__ h, const int* __restrict__ labels,
    const float* __restrict__ mask, const float* __restrict__ trans,
    const float* __restrict__ start_trans, const float* __restrict__ end_trans,
    float* __restrict__ num_out)
{
    const int b = blockIdx.x;
    const int tid = threadIdx.x;
    const int* lab = labels + b * Tt;
    const float* mk = mask + b * Tt;
    const float* hb = h + (size_t)b * Tt * Ll;

    float acc = 0.f;
    float msum = 0.f;
    for (int t = tid; t < Tt; t += 256) {
        int lt = lab[t];
        float mt = mk[t];
        msum += mt;
        if (t < Tt - 1) {
            int lt1 = lab[t + 1];
            acc += hb[t * Ll + lt] * mt + trans[lt * Ll + lt1] * mk[t + 1];
        }
    }
    for (int off = 32; off; off >>= 1) {
        acc  += __shfl_down(acc, off, 64);
        msum += __shfl_down(msum, off, 64);
    }
    __shared__ float racc[4], rmsum[4];
    const int wave = tid >> 6;
    if ((tid & 63) == 0) { racc[wave] = acc; rmsum[wave] = msum; }
    __syncthreads();
    if (tid == 0) {
        float a = racc[0] + racc[1] + racc[2] + racc[3];
        float m = rmsum[0] + rmsum[1] + rmsum[2] + rmsum[3];
        int last_idx = (int)(m + 0.5f) - 1;
        if (last_idx < 0) last_idx = 0;
        if (last_idx > Tt - 1) last_idx = Tt - 1;
        int last_lab = lab[last_idx];
        float num = a + start_trans[lab[0]];
        num += hb[(Tt - 1) * Ll + last_lab] * mk[Tt - 1];
        num += end_trans[last_lab];
        num_out[b] = num;
    }
}

// ---------------- denominator (forward scan) kernel ----------------
// R6 skeleton (4 waves, pair-split matvec, LDS-only s_barrier, 3-deep h
// prefetch) with three DS-pipe / critical-path fixes:
//  1. p bank-padded: halves at float offsets 0 and 68 -> the two broadcast
//     ds_read_b128 addresses hit disjoint bank quads (was: identical banks,
//     6.7e7 conflict cycles invariant across R1-R6).
//  2. pair-reduce via DPP quad_perm(1,0,3,2) (VALU) instead of __shfl_xor
//     (ds_bpermute, DS pipe + ~120cy latency on the critical path).
//  3. exp-domain p update: p_t[j] = acc[j]*exp(h_t[j]+S_{t-1}-S_t); the exp
//     factor uses only prefetched h + shift ring -> computed under the
//     matvec. Critical path after reduce: 1 fma + ds_write. log survives
//     only in the score tracker (off the inter-wave dependency).
// Mask exact: p = fma(acc, eh*m, pw*exp(dS)*(1-m)); score blend as before.
__global__ __launch_bounds__(256)
__attribute__((amdgpu_waves_per_eu(1, 2)))
void crf_den_kernel(
    const float* __restrict__ h, const float* __restrict__ mask,
    const float* __restrict__ expT, const float* __restrict__ start_trans,
    const float* __restrict__ end_trans, const float* __restrict__ num_in,
    float* __restrict__ out)
{
    __shared__ float p_lds[2][Ll + 4];   // halves at [0..63] and [68..131]
    __shared__ float sc0[3];
    __shared__ float redm[4], reds[4];

    const int b = blockIdx.x;
    const int tid = threadIdx.x;
    const int wave = tid >> 6;
    const int lane = tid & 63;
    const int j = (wave << 5) + (lane >> 1);   // column 0..127
    const int ihalf = lane & 1;                // i-range: 0 -> [0,64), 1 -> [64,128)
    const int jpad = j + ((j >> 6) << 2);      // padded write index
    const float SH = 16.0f;

    const float* hb = h + (size_t)b * Tt * Ll;
    const float* mk = mask + b * Tt;

    // exp(trans) fragment: 16 named float4 = 64 VGPRs, contiguous load
    const float4* ep = (const float4*)(expT + j * Ll + (ihalf << 6));
    float4 e0  = ep[0],  e1  = ep[1],  e2  = ep[2],  e3  = ep[3];
    float4 e4  = ep[4],  e5  = ep[5],  e6  = ep[6],  e7  = ep[7];
    float4 e8  = ep[8],  e9  = ep[9],  e10 = ep[10], e11 = ep[11];
    float4 e12 = ep[12], e13 = ep[13], e14 = ep[14], e15 = ep[15];

    // bootstrap t = 0
    float score = start_trans[j] + hb[j];
    if (tid == 0) { sc0[0] = score; sc0[2] = score; }
    __syncthreads();
    float pw = __expf(score - (sc0[0] + SH));
    p_lds[0][jpad] = pw;
    __syncthreads();   // prologue: full barrier fine (once)

    // 3-deep register pipelines for h and mask (issued after prologue)
    float hc = hb[1 * Ll + j];
    float hn = hb[2 * Ll + j];
    float hp = hb[3 * Ll + j];
    float mc = mk[1], mn2 = mk[2], mp2 = mk[3];

    const float4* pb0 = (const float4*)(&p_lds[0][ihalf ? 68 : 0]);
    const float4* pb1 = (const float4*)(&p_lds[1][ihalf ? 68 : 0]);

    int cbuf = 0;
    for (int t = 1; t < Tt; ++t) {
        // shift ring reads + this step's prefetch issue (t+3)
        float Sb = sc0[(t + 1) % 3] + SH;   // S_{t-1}: shift inside current p
        float Sf = sc0[(t + 2) % 3] + SH;   // S_t:     shift for new p
        int tp = (t + 3 < Tt) ? (t + 3) : (Tt - 1);
        float hq = hb[tp * Ll + j];
        float mq = mk[tp];

        // exp factors: independent of acc -> scheduled under the matvec
        float dS  = Sb - Sf;
        float mt  = mc;
        float c1  = __expf(hc + dS) * mt;              // acc coefficient
        float c0  = pw * __expf(dS) * (1.f - mt);      // masked carry term

        // matvec: 64 FMAs over this lane's i-half, p read as broadcast float4
        const float4* pp = cbuf ? pb1 : pb0;
        float a0 = 0.f, a1 = 0.f, a2 = 0.f, a3 = 0.f;
#define FMA4(E, K) { float4 pv = pp[K];              \
        a0 = fmaf(pv.x, E.x, a0);                    \
        a1 = fmaf(pv.y, E.y, a1);                    \
        a2 = fmaf(pv.z, E.z, a2);                    \
        a3 = fmaf(pv.w, E.w, a3); }
        FMA4(e0, 0)   FMA4(e1, 1)   FMA4(e2, 2)   FMA4(e3, 3)
        FMA4(e4, 4)   FMA4(e5, 5)   FMA4(e6, 6)   FMA4(e7, 7)
        FMA4(e8, 8)   FMA4(e9, 9)   FMA4(e10, 10) FMA4(e11, 11)
        FMA4(e12, 12) FMA4(e13, 13) FMA4(e14, 14) FMA4(e15, 15)
#undef FMA4
        float acc = (a0 + a1) + (a2 + a3);
        // pair-reduce via DPP quad_perm(1,0,3,2): VALU, no DS pipe
        acc += __int_as_float(__builtin_amdgcn_update_dpp(
                   0, __float_as_int(acc), 0xB1, 0xF, 0xF, true));

        // p update: single fma on the critical path, then store
        float pn = fmaf(acc, c1, c0);
        p_lds[cbuf ^ 1][jpad] = pn;

        // score tracker (off the p path; only tid0's sc0 write is a dependency)
        float upd = hc + Sb + __logf(acc);
        score = mt * upd + (1.f - mt) * score;
        if (tid == 0) sc0[t % 3] = score;

        pw = pn;
        hc = hn; hn = hp; hp = hq;
        mc = mn2; mn2 = mp2; mp2 = mq;

        // LDS-only sync: vmcnt NOT drained; h/mask prefetches stay in flight
        asm volatile("s_waitcnt lgkmcnt(0)\n\ts_barrier" ::: "memory");
        cbuf ^= 1;
    }

    // ---- final logsumexp over score + end_trans ----
    float v = score + end_trans[j];
    float mval = ((lane & 1) == 0) ? v : -1e30f;
    #pragma unroll
    for (int off = 32; off; off >>= 1) mval = fmaxf(mval, __shfl_xor(mval, off, 64));
    if (lane == 0) redm[wave] = mval;
    __syncthreads();
    float M = fmaxf(fmaxf(redm[0], redm[1]), fmaxf(redm[2], redm[3]));
    float e = ((lane & 1) == 0) ? __expf(v - M) : 0.f;
    #pragma unroll
    for (int off = 32; off; off >>= 1) e += __shfl_xor(e, off, 64);
    if (lane == 0) reds[wave] = e;
    __syncthreads();
    if (tid == 0) {
        float den = M + __logf(reds[0] + reds[1] + reds[2] + reds[3]);
        out[b] = num_in[b] - den;
    }
}

extern "C" void kernel_launch(void* const* d_in, const int* in_sizes, int n_in,
                              void* d_out, int out_size, void* d_ws, size_t ws_size,
                              hipStream_t stream) {
    const float* h           = (const float*)d_in[0];
    const int*   labels      = (const int*)d_in[1];
    const float* mask        = (const float*)d_in[2];
    const float* trans       = (const float*)d_in[3];
    const float* start_trans = (const float*)d_in[4];
    const float* end_trans   = (const float*)d_in[5];
    float* out    = (float*)d_out;
    float* num_ws = (float*)d_ws;                 // [0, 256)         num results
    float* expT   = (float*)d_ws + 256;           // [256, 256+16384) exp(trans)^T

    crf_expT_kernel<<<(Ll * Ll + 255) / 256, 256, 0, stream>>>(trans, expT);
    crf_num_kernel<<<Bb, 256, 0, stream>>>(h, labels, mask, trans, start_trans, end_trans, num_ws);
    crf_den_kernel<<<Bb, 256, 0, stream>>>(h, mask, expT, start_trans, end_trans, num_ws, out);
}

// Round 8
// 461.432 us; speedup vs baseline: 1.3058x; 1.3058x over previous
//
#include <hip/hip_runtime.h>
#include <math.h>

#define Bb 256
#define Tt 1024
#define Ll 128

// ---------------- exp(trans) transpose precompute ----------------
// expT[j*128 + i] = exp(trans[i*128 + j])
__global__ __launch_bounds__(256) void crf_expT_kernel(
    const float* __restrict__ trans, float* __restrict__ expT)
{
    int idx = blockIdx.x * 256 + threadIdx.x;   // idx = j*128 + i
    if (idx < Ll * Ll) {
        int jj = idx >> 7;
        int ii = idx & (Ll - 1);
        expT[idx] = __expf(trans[ii * Ll + jj]);
    }
}

// ---------------- numerator kernel ----------------
__global__ __launch_bounds__(256) void crf_num_kernel(
    const float* __restrict__ h, const int* __restrict__ labels,
    const float* __restrict__ mask, const float* __restrict__ trans,
    const float* __restrict__ start_trans, const float* __restrict__ end_trans,
    float* __restrict__ num_out)
{
    const int b = blockIdx.x;
    const int tid = threadIdx.x;
    const int* lab = labels + b * Tt;
    const float* mk = mask + b * Tt;
    const float* hb = h + (size_t)b * Tt * Ll;

    float acc = 0.f;
    float msum = 0.f;
    for (int t = tid; t < Tt; t += 256) {
        int lt = lab[t];
        float mt = mk[t];
        msum += mt;
        if (t < Tt - 1) {
            int lt1 = lab[t + 1];
            acc += hb[t * Ll + lt] * mt + trans[lt * Ll + lt1] * mk[t + 1];
        }
    }
    for (int off = 32; off; off >>= 1) {
        acc  += __shfl_down(acc, off, 64);
        msum += __shfl_down(msum, off, 64);
    }
    __shared__ float racc[4], rmsum[4];
    const int wave = tid >> 6;
    if ((tid & 63) == 0) { racc[wave] = acc; rmsum[wave] = msum; }
    __syncthreads();
    if (tid == 0) {
        float a = racc[0] + racc[1] + racc[2] + racc[3];
        float m = rmsum[0] + rmsum[1] + rmsum[2] + rmsum[3];
        int last_idx = (int)(m + 0.5f) - 1;
        if (last_idx < 0) last_idx = 0;
        if (last_idx > Tt - 1) last_idx = Tt - 1;
        int last_lab = lab[last_idx];
        float num = a + start_trans[lab[0]];
        num += hb[(Tt - 1) * Ll + last_lab] * mk[Tt - 1];
        num += end_trans[last_lab];
        num_out[b] = num;
    }
}

// ---------------- denominator (forward scan) kernel ----------------
// DS-pipe diet: R1-R7 all issued ~64 ds_read_b128/step/CU (each of 256
// threads read its full 64-float p range) -> ~770cy/step on the one LDS
// pipe = the invariant ~1400cy/step. Now each thread owns 4 COLUMNS x 16
// i-values: reads only 16 p floats (4x ds_read_b128), reuses each 4x from
// registers -> 16 read-instr/step/CU. Partial sums reduced across the 8
// i-slices on the VALU via DPP (xor1 0xB1, xor2 0x4E, half-mirror 0x141).
// p layout padded addr(i) = i + (i>>4)*4 -> the 8 islice read-bases hit 8
// disjoint 4-bank groups (20*s mod 32 all distinct) = conflict-free.
// Shift ring: float2 slot (score_t[0], score_{t-1}[0]) -> ONE ds_read_b64.
// Exp-domain p update + LDS-only s_barrier (no vmcnt drain) kept from R6/R7.
__global__ __launch_bounds__(256)
__attribute__((amdgpu_waves_per_eu(1, 2)))
void crf_den_kernel(
    const float* __restrict__ h, const float* __restrict__ mask,
    const float* __restrict__ expT, const float* __restrict__ start_trans,
    const float* __restrict__ end_trans, const float* __restrict__ num_in,
    float* __restrict__ out)
{
    __shared__ float p_lds[2][160];      // padded: addr(i) = i + (i>>4)*4
    __shared__ float2 ring[4];           // (score_t[0], score_{t-1}[0])
    __shared__ float redm[4], reds[4];

    const int b = blockIdx.x;
    const int tid = threadIdx.x;
    const int wave = tid >> 6;
    const int lane = tid & 63;
    const int jgrp = lane >> 3;              // 8 column-groups per wave
    const int isl  = lane & 7;               // i-slice 0..7 (16 i each)
    const int jbase = (wave << 5) + (jgrp << 2);   // 4 columns per thread
    const int wcol  = jbase + (isl & 3);     // column this lane writes/tracks
    const bool writer = (isl < 4);
    const int waddr = wcol + ((wcol >> 4) << 2);
    const float SH = 16.0f;

    const float* hb = h + (size_t)b * Tt * Ll;
    const float* mk = mask + b * Tt;

    // E fragment: cols jbase+0..3, i in [isl*16, isl*16+16) -> 16 float4
    const float4* E0p = (const float4*)(expT + (jbase + 0) * Ll + (isl << 4));
    const float4* E1p = (const float4*)(expT + (jbase + 1) * Ll + (isl << 4));
    const float4* E2p = (const float4*)(expT + (jbase + 2) * Ll + (isl << 4));
    const float4* E3p = (const float4*)(expT + (jbase + 3) * Ll + (isl << 4));
    float4 E00=E0p[0],E01=E0p[1],E02=E0p[2],E03=E0p[3];
    float4 E10=E1p[0],E11=E1p[1],E12=E1p[2],E13=E1p[3];
    float4 E20=E2p[0],E21=E2p[1],E22=E2p[2],E23=E2p[3];
    float4 E30=E3p[0],E31=E3p[1],E32=E3p[2],E33=E3p[3];

    // bootstrap t = 0
    float score = start_trans[wcol] + hb[wcol];
    if (tid == 0) ring[0] = make_float2(score, score);
    __syncthreads();
    float pw = __expf(score - (ring[0].y + SH));
    if (writer) p_lds[0][waddr] = pw;
    __syncthreads();   // prologue: full barriers fine (once)

    // 3-deep register pipelines (issued after prologue; never drained by
    // the in-loop LDS-only barrier -> stay in flight across steps)
    float hc = hb[1 * Ll + wcol];
    float hn = hb[2 * Ll + wcol];
    float hp = hb[3 * Ll + wcol];
    float mc = mk[1], mn = mk[2], mp = mk[3];

    const float* pbA = &p_lds[0][isl * 20];
    const float* pbB = &p_lds[1][isl * 20];
    float* wrA = &p_lds[1][waddr];    // cbuf=0: read buf0, write buf1
    float* wrB = &p_lds[0][waddr];

#define DPPA(x, ctrl) __int_as_float(__builtin_amdgcn_update_dpp( \
        0, __float_as_int(x), ctrl, 0xF, 0xF, true))

    int cbuf = 0;
    for (int t = 1; t < Tt; ++t) {
        // ring read (broadcast b64) + prefetch issue for t+3
        float2 rr = ring[(t - 1) & 3];
        float Sb = rr.y + SH;             // S_{t-1}: shift inside current p
        float Sf = rr.x + SH;             // S_t:     shift for new p
        int tp = (t + 3 < Tt) ? (t + 3) : (Tt - 1);
        float hq = hb[tp * Ll + wcol];
        float mq = mk[tp];

        // exp factors: independent of acc -> scheduled under the matvec
        float dS = Sb - Sf;
        float mt = mc;
        float c1 = __expf(hc + dS) * mt;             // acc coefficient
        float c0 = pw * __expf(dS) * (1.f - mt);     // masked carry term

        // p fragment: 16 floats via 4 conflict-free ds_read_b128
        const float4* pp = (const float4*)(cbuf ? pbB : pbA);
        float4 p0 = pp[0], p1 = pp[1], p2 = pp[2], p3 = pp[3];

        float a0 = 0.f, a1 = 0.f, a2 = 0.f, a3 = 0.f;
#define DOT(acc, X0, X1, X2, X3)                                   \
        acc = fmaf(p0.x, X0.x, acc); acc = fmaf(p0.y, X0.y, acc);  \
        acc = fmaf(p0.z, X0.z, acc); acc = fmaf(p0.w, X0.w, acc);  \
        acc = fmaf(p1.x, X1.x, acc); acc = fmaf(p1.y, X1.y, acc);  \
        acc = fmaf(p1.z, X1.z, acc); acc = fmaf(p1.w, X1.w, acc);  \
        acc = fmaf(p2.x, X2.x, acc); acc = fmaf(p2.y, X2.y, acc);  \
        acc = fmaf(p2.z, X2.z, acc); acc = fmaf(p2.w, X2.w, acc);  \
        acc = fmaf(p3.x, X3.x, acc); acc = fmaf(p3.y, X3.y, acc);  \
        acc = fmaf(p3.z, X3.z, acc); acc = fmaf(p3.w, X3.w, acc);
        DOT(a0, E00, E01, E02, E03)
        DOT(a1, E10, E11, E12, E13)
        DOT(a2, E20, E21, E22, E23)
        DOT(a3, E30, E31, E32, E33)
#undef DOT

        // reduce across the 8 i-slices: VALU-only DPP butterfly
        a0 += DPPA(a0, 0xB1); a0 += DPPA(a0, 0x4E); a0 += DPPA(a0, 0x141);
        a1 += DPPA(a1, 0xB1); a1 += DPPA(a1, 0x4E); a1 += DPPA(a1, 0x141);
        a2 += DPPA(a2, 0xB1); a2 += DPPA(a2, 0x4E); a2 += DPPA(a2, 0x141);
        a3 += DPPA(a3, 0xB1); a3 += DPPA(a3, 0x4E); a3 += DPPA(a3, 0x141);

        // select this lane's column sum (col = jbase + (isl&3))
        float s01 = (isl & 1) ? a1 : a0;
        float s23 = (isl & 1) ? a3 : a2;
        float accsel = (isl & 2) ? s23 : s01;

        // p update: one fma on the critical path, then store
        float pn = fmaf(accsel, c1, c0);
        if (writer) *(cbuf ? wrB : wrA) = pn;

        // score tracker (off the p critical path)
        float sc_old = score;
        float upd = hc + Sb + __logf(accsel);
        score = mt * upd + (1.f - mt) * score;
        if (tid == 0) ring[t & 3] = make_float2(score, sc_old);

        pw = pn;
        hc = hn; hn = hp; hp = hq;
        mc = mn; mn = mp; mp = mq;

        // LDS-only sync: vmcnt NOT drained; prefetches stay in flight
        asm volatile("s_waitcnt lgkmcnt(0)\n\ts_barrier" ::: "memory");
        cbuf ^= 1;
    }
#undef DPPA

    // ---- final logsumexp over score + end_trans ----
    // lanes isl and isl+4 hold the same column score; count writers only
    float v = score + end_trans[wcol];
    float mval = writer ? v : -1e30f;
    #pragma unroll
    for (int off = 32; off; off >>= 1) mval = fmaxf(mval, __shfl_xor(mval, off, 64));
    if (lane == 0) redm[wave] = mval;
    __syncthreads();
    float M = fmaxf(fmaxf(redm[0], redm[1]), fmaxf(redm[2], redm[3]));
    float e = writer ? __expf(v - M) : 0.f;
    #pragma unroll
    for (int off = 32; off; off >>= 1) e += __shfl_xor(e, off, 64);
    if (lane == 0) reds[wave] = e;
    __syncthreads();
    if (tid == 0) {
        float den = M + __logf(reds[0] + reds[1] + reds[2] + reds[3]);
        out[b] = num_in[b] - den;
    }
}

extern "C" void kernel_launch(void* const* d_in, const int* in_sizes, int n_in,
                              void* d_out, int out_size, void* d_ws, size_t ws_size,
                              hipStream_t stream) {
    const float* h           = (const float*)d_in[0];
    const int*   labels      = (const int*)d_in[1];
    const float* mask        = (const float*)d_in[2];
    const float* trans       = (const float*)d_in[3];
    const float* start_trans = (const float*)d_in[4];
    const float* end_trans   = (const float*)d_in[5];
    float* out    = (float*)d_out;
    float* num_ws = (float*)d_ws;                 // [0, 256)         num results
    float* expT   = (float*)d_ws + 256;           // [256, 256+16384) exp(trans)^T

    crf_expT_kernel<<<(Ll * Ll + 255) / 256, 256, 0, stream>>>(trans, expT);
    crf_num_kernel<<<Bb, 256, 0, stream>>>(h, labels, mask, trans, start_trans, end_trans, num_ws);
    crf_den_kernel<<<Bb, 256, 0, stream>>>(h, mask, expT, start_trans, end_trans, num_ws, out);
}

// Round 9
// 335.573 us; speedup vs baseline: 1.7955x; 1.3751x over previous
//
#include <hip/hip_runtime.h>
#include <math.h>

#define Bb 256
#define Tt 1024
#define Ll 128

// ---------------- exp(trans) transpose precompute ----------------
// expT[j*128 + i] = exp(trans[i*128 + j])
__global__ __launch_bounds__(256) void crf_expT_kernel(
    const float* __restrict__ trans, float* __restrict__ expT)
{
    int idx = blockIdx.x * 256 + threadIdx.x;   // idx = j*128 + i
    if (idx < Ll * Ll) {
        int jj = idx >> 7;
        int ii = idx & (Ll - 1);
        expT[idx] = __expf(trans[ii * Ll + jj]);
    }
}

// ---------------- numerator kernel ----------------
__global__ __launch_bounds__(256) void crf_num_kernel(
    const float* __restrict__ h, const int* __restrict__ labels,
    const float* __restrict__ mask, const float* __restrict__ trans,
    const float* __restrict__ start_trans, const float* __restrict__ end_trans,
    float* __restrict__ num_out)
{
    const int b = blockIdx.x;
    const int tid = threadIdx.x;
    const int* lab = labels + b * Tt;
    const float* mk = mask + b * Tt;
    const float* hb = h + (size_t)b * Tt * Ll;

    float acc = 0.f;
    float msum = 0.f;
    for (int t = tid; t < Tt; t += 256) {
        int lt = lab[t];
        float mt = mk[t];
        msum += mt;
        if (t < Tt - 1) {
            int lt1 = lab[t + 1];
            acc += hb[t * Ll + lt] * mt + trans[lt * Ll + lt1] * mk[t + 1];
        }
    }
    for (int off = 32; off; off >>= 1) {
        acc  += __shfl_down(acc, off, 64);
        msum += __shfl_down(msum, off, 64);
    }
    __shared__ float racc[4], rmsum[4];
    const int wave = tid >> 6;
    if ((tid & 63) == 0) { racc[wave] = acc; rmsum[wave] = msum; }
    __syncthreads();
    if (tid == 0) {
        float a = racc[0] + racc[1] + racc[2] + racc[3];
        float m = rmsum[0] + rmsum[1] + rmsum[2] + rmsum[3];
        int last_idx = (int)(m + 0.5f) - 1;
        if (last_idx < 0) last_idx = 0;
        if (last_idx > Tt - 1) last_idx = Tt - 1;
        int last_lab = lab[last_idx];
        float num = a + start_trans[lab[0]];
        num += hb[(Tt - 1) * Ll + last_lab] * mk[Tt - 1];
        num += end_trans[last_lab];
        num_out[b] = num;
    }
}

// ---------------- denominator (forward scan) kernel ----------------
// R8 layout (4 waves, C=4 cols x I=16 i per thread, DPP butterfly, padded p,
// LDS-only barrier) with the latency bug fixed:
//  * SLOT REFILL, unroll x4: body t loads h/mask directly into slot t&3,
//    consumed 3 bodies (~1100cy) later. R1-R8's rotating pipeline (hp=hq)
//    read the just-issued load -> s_waitcnt vmcnt exposed full L3/HBM
//    latency (~700cy) EVERY step. No rotation -> no exposed latency.
//  * Shift update every 4th step: between updates dS=0, c1=exp(h)*m is
//    prepared one body ahead from prefetched h (off critical path). At
//    update bodies: e^{dS} = e^{-16}/p[0] via broadcast ds_read_b32 + fast
//    divide (no exp/log on the p path). S tracked additively; final
//    score_j = log(p_T[j]) + S. LDS ring + per-step log/score: deleted.
//    Scale drift over 4 steps stays within e^{-18}..e^{+27} (fp32-safe).
__global__ __launch_bounds__(256)
__attribute__((amdgpu_waves_per_eu(1, 1)))
void crf_den_kernel(
    const float* __restrict__ h, const float* __restrict__ mask,
    const float* __restrict__ expT, const float* __restrict__ start_trans,
    const float* __restrict__ end_trans, const float* __restrict__ num_in,
    float* __restrict__ out)
{
    __shared__ float p_lds[2][160];      // padded: addr(i) = i + (i>>4)*4
    __shared__ float redm[4], reds[4];

    const int b = blockIdx.x;
    const int tid = threadIdx.x;
    const int wave = tid >> 6;
    const int lane = tid & 63;
    const int jgrp = lane >> 3;                    // 8 column-groups per wave
    const int isl  = lane & 7;                     // i-slice 0..7 (16 i each)
    const int jbase = (wave << 5) + (jgrp << 2);   // 4 columns per thread
    const int wcol  = jbase + (isl & 3);           // column this lane writes
    const bool writer = (isl < 4);
    const int waddr = wcol + ((wcol >> 4) << 2);

    const float* hb = h + (size_t)b * Tt * Ll;
    const float* mk = mask + b * Tt;

    // E fragment: cols jbase+0..3, i in [isl*16, isl*16+16) -> 16 float4
    const float4* E0p = (const float4*)(expT + (jbase + 0) * Ll + (isl << 4));
    const float4* E1p = (const float4*)(expT + (jbase + 1) * Ll + (isl << 4));
    const float4* E2p = (const float4*)(expT + (jbase + 2) * Ll + (isl << 4));
    const float4* E3p = (const float4*)(expT + (jbase + 3) * Ll + (isl << 4));
    float4 E00=E0p[0],E01=E0p[1],E02=E0p[2],E03=E0p[3];
    float4 E10=E1p[0],E11=E1p[1],E12=E1p[2],E13=E1p[3];
    float4 E20=E2p[0],E21=E2p[1],E22=E2p[2],E23=E2p[3];
    float4 E30=E3p[0],E31=E3p[1],E32=E3p[2],E33=E3p[3];

    // bootstrap t = 0: shift S0 = score_0[0] + 16, computed uniformly
    float S = start_trans[0] + hb[0] + 16.0f;
    float score0 = start_trans[wcol] + hb[wcol];
    float pw = __expf(score0 - S);
    if (writer) p_lds[0][waddr] = pw;

    // h/mask slots (slot r holds data for time t with t&3 == r)
    float h1 = hb[1 * Ll + wcol], m1 = mk[1];
    float h2 = hb[2 * Ll + wcol], m2 = mk[2];
    float h3 = hb[3 * Ll + wcol], m3 = mk[3];
    float h0 = hb[4 * Ll + wcol], m0 = mk[4];
    __syncthreads();

    float ex1 = __expf(h1) * m1, om1 = 1.f - m1;
    float ex0, om0, ex2, om2, ex3, om3;

#define DPPA(x, ctrl) __int_as_float(__builtin_amdgcn_update_dpp( \
        0, __float_as_int(x), ctrl, 0xF, 0xF, true))

    // BODY: one scan step. RBUF = buffer read (write RBUF^1). UPD = shift
    // update step. EXc/OMc = this step's coeffs (prepared last body).
    // EXn/OMn prepared here from slot (HN,MN) for the NEXT body.
    // (HR,MR) refilled with time TR = t+4 (clamped) -- consumed 3 bodies later.
#define BODY(RBUF, UPD, EXc, OMc, HN, MN, EXn, OMn, HR, MR, TR) {      \
    const float4* pp = (const float4*)(&p_lds[RBUF][isl * 20]);        \
    float4 q0 = pp[0], q1 = pp[1], q2 = pp[2], q3 = pp[3];             \
    float pz = 0.f;                                                    \
    if (UPD) pz = p_lds[RBUF][0];                                      \
    HR = hb[(TR) * Ll + wcol];                                         \
    MR = mk[(TR)];                                                     \
    float a0 = 0.f, a1 = 0.f, a2 = 0.f, a3 = 0.f;                      \
    DOT(a0, E00, E01, E02, E03)                                        \
    DOT(a1, E10, E11, E12, E13)                                        \
    DOT(a2, E20, E21, E22, E23)                                        \
    DOT(a3, E30, E31, E32, E33)                                        \
    a0 += DPPA(a0,0xB1); a0 += DPPA(a0,0x4E); a0 += DPPA(a0,0x141);    \
    a1 += DPPA(a1,0xB1); a1 += DPPA(a1,0x4E); a1 += DPPA(a1,0x141);    \
    a2 += DPPA(a2,0xB1); a2 += DPPA(a2,0x4E); a2 += DPPA(a2,0x141);    \
    a3 += DPPA(a3,0xB1); a3 += DPPA(a3,0x4E); a3 += DPPA(a3,0x141);    \
    float s01 = (isl & 1) ? a1 : a0;                                   \
    float s23 = (isl & 1) ? a3 : a2;                                   \
    float acc = (isl & 2) ? s23 : s01;                                 \
    float c1 = EXc, c0 = pw * OMc;                                     \
    if (UPD) { float ed = __fdividef(1.12535175e-7f, pz);              \
               c1 *= ed; c0 *= ed; S += __logf(pz) + 16.0f; }          \
    float pn = fmaf(acc, c1, c0);                                      \
    if (writer) p_lds[(RBUF) ^ 1][waddr] = pn;                         \
    EXn = __expf(HN) * MN; OMn = 1.f - MN;                             \
    pw = pn;                                                           \
    asm volatile("s_waitcnt lgkmcnt(0)\n\ts_barrier" ::: "memory");    \
}

#define DOT(acc, X0, X1, X2, X3)                                   \
        acc = fmaf(q0.x, X0.x, acc); acc = fmaf(q0.y, X0.y, acc);  \
        acc = fmaf(q0.z, X0.z, acc); acc = fmaf(q0.w, X0.w, acc);  \
        acc = fmaf(q1.x, X1.x, acc); acc = fmaf(q1.y, X1.y, acc);  \
        acc = fmaf(q1.z, X1.z, acc); acc = fmaf(q1.w, X1.w, acc);  \
        acc = fmaf(q2.x, X2.x, acc); acc = fmaf(q2.y, X2.y, acc);  \
        acc = fmaf(q2.z, X2.z, acc); acc = fmaf(q2.w, X2.w, acc);  \
        acc = fmaf(q3.x, X3.x, acc); acc = fmaf(q3.y, X3.y, acc);  \
        acc = fmaf(q3.z, X3.z, acc); acc = fmaf(q3.w, X3.w, acc);

    // pre-loop bodies: t = 1, 2, 3 (regular; S unchanged)
    BODY(0, 0, ex1, om1, h2, m2, ex2, om2, h1, m1, 5)
    BODY(1, 0, ex2, om2, h3, m3, ex3, om3, h2, m2, 6)
    BODY(0, 0, ex3, om3, h0, m0, ex0, om0, h3, m3, 7)

    // main loop: k = 1..255, t = 4k (update), 4k+1, 4k+2, 4k+3
    for (int k = 1; k < 256; ++k) {
        int t4 = k << 2;
        int r0 = t4 + 4 > Tt - 1 ? Tt - 1 : t4 + 4;
        int r1 = t4 + 5 > Tt - 1 ? Tt - 1 : t4 + 5;
        int r2 = t4 + 6 > Tt - 1 ? Tt - 1 : t4 + 6;
        int r3 = t4 + 7 > Tt - 1 ? Tt - 1 : t4 + 7;
        BODY(1, 1, ex0, om0, h1, m1, ex1, om1, h0, m0, r0)
        BODY(0, 0, ex1, om1, h2, m2, ex2, om2, h1, m1, r1)
        BODY(1, 0, ex2, om2, h3, m3, ex3, om3, h2, m2, r2)
        BODY(0, 0, ex3, om3, h0, m0, ex0, om0, h3, m3, r3)
    }
#undef DOT
#undef BODY
#undef DPPA

    // ---- final logsumexp: score_j = log(p_T[j]) + S ----
    float v = __logf(pw) + S + end_trans[wcol];
    float mval = writer ? v : -1e30f;
    #pragma unroll
    for (int off = 32; off; off >>= 1) mval = fmaxf(mval, __shfl_xor(mval, off, 64));
    if (lane == 0) redm[wave] = mval;
    __syncthreads();
    float M = fmaxf(fmaxf(redm[0], redm[1]), fmaxf(redm[2], redm[3]));
    float e = writer ? __expf(v - M) : 0.f;
    #pragma unroll
    for (int off = 32; off; off >>= 1) e += __shfl_xor(e, off, 64);
    if (lane == 0) reds[wave] = e;
    __syncthreads();
    if (tid == 0) {
        float den = M + __logf(reds[0] + reds[1] + reds[2] + reds[3]);
        out[b] = num_in[b] - den;
    }
}

extern "C" void kernel_launch(void* const* d_in, const int* in_sizes, int n_in,
                              void* d_out, int out_size, void* d_ws, size_t ws_size,
                              hipStream_t stream) {
    const float* h           = (const float*)d_in[0];
    const int*   labels      = (const int*)d_in[1];
    const float* mask        = (const float*)d_in[2];
    const float* trans       = (const float*)d_in[3];
    const float* start_trans = (const float*)d_in[4];
    const float* end_trans   = (const float*)d_in[5];
    float* out    = (float*)d_out;
    float* num_ws = (float*)d_ws;                 // [0, 256)         num results
    float* expT   = (float*)d_ws + 256;           // [256, 256+16384) exp(trans)^T

    crf_expT_kernel<<<(Ll * Ll + 255) / 256, 256, 0, stream>>>(trans, expT);
    crf_num_kernel<<<Bb, 256, 0, stream>>>(h, labels, mask, trans, start_trans, end_trans, num_ws);
    crf_den_kernel<<<Bb, 256, 0, stream>>>(h, mask, expT, start_trans, end_trans, num_ws, out);
}

// Round 10
// 262.917 us; speedup vs baseline: 2.2917x; 1.2763x over previous
//
#include <hip/hip_runtime.h>
#include <math.h>

#define Bb 256
#define Tt 1024
#define Ll 128

typedef float v2f __attribute__((ext_vector_type(2)));

// ---------------- exp(trans) transpose precompute ----------------
// expT[j*128 + i] = exp(trans[i*128 + j])
__global__ __launch_bounds__(256) void crf_expT_kernel(
    const float* __restrict__ trans, float* __restrict__ expT)
{
    int idx = blockIdx.x * 256 + threadIdx.x;   // idx = j*128 + i
    if (idx < Ll * Ll) {
        int jj = idx >> 7;
        int ii = idx & (Ll - 1);
        expT[idx] = __expf(trans[ii * Ll + jj]);
    }
}

// ---------------- numerator kernel ----------------
__global__ __launch_bounds__(256) void crf_num_kernel(
    const float* __restrict__ h, const int* __restrict__ labels,
    const float* __restrict__ mask, const float* __restrict__ trans,
    const float* __restrict__ start_trans, const float* __restrict__ end_trans,
    float* __restrict__ num_out)
{
    const int b = blockIdx.x;
    const int tid = threadIdx.x;
    const int* lab = labels + b * Tt;
    const float* mk = mask + b * Tt;
    const float* hb = h + (size_t)b * Tt * Ll;

    float acc = 0.f;
    float msum = 0.f;
    for (int t = tid; t < Tt; t += 256) {
        int lt = lab[t];
        float mt = mk[t];
        msum += mt;
        if (t < Tt - 1) {
            int lt1 = lab[t + 1];
            acc += hb[t * Ll + lt] * mt + trans[lt * Ll + lt1] * mk[t + 1];
        }
    }
    for (int off = 32; off; off >>= 1) {
        acc  += __shfl_down(acc, off, 64);
        msum += __shfl_down(msum, off, 64);
    }
    __shared__ float racc[4], rmsum[4];
    const int wave = tid >> 6;
    if ((tid & 63) == 0) { racc[wave] = acc; rmsum[wave] = msum; }
    __syncthreads();
    if (tid == 0) {
        float a = racc[0] + racc[1] + racc[2] + racc[3];
        float m = rmsum[0] + rmsum[1] + rmsum[2] + rmsum[3];
        int last_idx = (int)(m + 0.5f) - 1;
        if (last_idx < 0) last_idx = 0;
        if (last_idx > Tt - 1) last_idx = Tt - 1;
        int last_lab = lab[last_idx];
        float num = a + start_trans[lab[0]];
        num += hb[(Tt - 1) * Ll + last_lab] * mk[Tt - 1];
        num += end_trans[last_lab];
        num_out[b] = num;
    }
}

// ---------------- denominator (forward scan) kernel ----------------
// R9 structure (4 waves, 4 cols x 16 i per thread, DPP butterfly, padded p,
// slot-refill x4 unroll, shift update every 4th step, LDS-only barrier),
// plus two fixes:
//  * MASK STAGED IN LDS: R9's refill mk[TR] had a wave-uniform address ->
//    compiler emits s_load_dword (SMEM, tracked by lgkmcnt). The per-step
//    "s_waitcnt lgkmcnt(0)" then drained a ~200-400cy SMEM load on the
//    critical path EVERY step. LDS broadcast ds_read_b32 instead.
//  * PACKED FP32 FMA: DOT written in float2 ext-vector arithmetic; clang
//    contracts to v_pk_fma_f32 -> 32 instr (64cy) instead of 64 (128cy).
//  * clamp-free main loop (k<255) + separate tail (refill clamp only there).
__global__ __launch_bounds__(256)
__attribute__((amdgpu_waves_per_eu(1, 1)))
void crf_den_kernel(
    const float* __restrict__ h, const float* __restrict__ mask,
    const float* __restrict__ expT, const float* __restrict__ start_trans,
    const float* __restrict__ end_trans, const float* __restrict__ num_in,
    float* __restrict__ out)
{
    __shared__ float p_lds[2][160];      // padded: addr(i) = i + (i>>4)*4
    __shared__ float mk_lds[Tt];         // staged mask row (4KB)
    __shared__ float redm[4], reds[4];

    const int b = blockIdx.x;
    const int tid = threadIdx.x;
    const int wave = tid >> 6;
    const int lane = tid & 63;
    const int jgrp = lane >> 3;                    // 8 column-groups per wave
    const int isl  = lane & 7;                     // i-slice 0..7 (16 i each)
    const int jbase = (wave << 5) + (jgrp << 2);   // 4 columns per thread
    const int wcol  = jbase + (isl & 3);           // column this lane writes
    const bool writer = (isl < 4);
    const int waddr = wcol + ((wcol >> 4) << 2);

    const float* hb = h + (size_t)b * Tt * Ll;
    const float* mk = mask + b * Tt;

    // stage mask row into LDS, vectorized (256 threads x float4 = 1024)
    ((float4*)mk_lds)[tid] = ((const float4*)mk)[tid];

    // E fragment: cols jbase+0..3, i in [isl*16, isl*16+16) -> 32 v2f regs
    const v2f* EAp = (const v2f*)(expT + (jbase + 0) * Ll + (isl << 4));
    const v2f* EBp = (const v2f*)(expT + (jbase + 1) * Ll + (isl << 4));
    const v2f* ECp = (const v2f*)(expT + (jbase + 2) * Ll + (isl << 4));
    const v2f* EDp = (const v2f*)(expT + (jbase + 3) * Ll + (isl << 4));
    v2f EA0=EAp[0],EA1=EAp[1],EA2=EAp[2],EA3=EAp[3],EA4=EAp[4],EA5=EAp[5],EA6=EAp[6],EA7=EAp[7];
    v2f EB0=EBp[0],EB1=EBp[1],EB2=EBp[2],EB3=EBp[3],EB4=EBp[4],EB5=EBp[5],EB6=EBp[6],EB7=EBp[7];
    v2f EC0=ECp[0],EC1=ECp[1],EC2=ECp[2],EC3=ECp[3],EC4=ECp[4],EC5=ECp[5],EC6=ECp[6],EC7=ECp[7];
    v2f ED0=EDp[0],ED1=EDp[1],ED2=EDp[2],ED3=EDp[3],ED4=EDp[4],ED5=EDp[5],ED6=EDp[6],ED7=EDp[7];

    // bootstrap t = 0: shift S0 = score_0[0] + 16, computed uniformly
    float S = start_trans[0] + hb[0] + 16.0f;
    float score0 = start_trans[wcol] + hb[wcol];
    float pw = __expf(score0 - S);
    if (writer) p_lds[0][waddr] = pw;

    // h/mask slots (slot r holds data for time t with t&3 == r)
    float h1 = hb[1 * Ll + wcol], m1 = mk[1];
    float h2 = hb[2 * Ll + wcol], m2 = mk[2];
    float h3 = hb[3 * Ll + wcol], m3 = mk[3];
    float h0 = hb[4 * Ll + wcol], m0 = mk[4];
    __syncthreads();

    float ex1 = __expf(h1) * m1, om1 = 1.f - m1;
    float ex0, om0, ex2, om2, ex3, om3;

#define DPPA(x, ctrl) __int_as_float(__builtin_amdgcn_update_dpp( \
        0, __float_as_int(x), ctrl, 0xF, 0xF, true))

    // BODY: one scan step. RBUF = buffer read (write RBUF^1). UPD = shift
    // update step. EXc/OMc = this step's coeffs (prepared last body).
    // EXn/OMn prepared here from slot (HN,MN) for the NEXT body.
    // (HR,MR) refilled with time TR (consumed 3 bodies later; h from global
    // [vmcnt, never drained], mask from LDS broadcast [lgkm, same-step ok]).
#define BODY(RBUF, UPD, EXc, OMc, HN, MN, EXn, OMn, HR, MR, TR) {      \
    const float4* pp = (const float4*)(&p_lds[RBUF][isl * 20]);        \
    float4 Q0 = pp[0], Q1 = pp[1], Q2 = pp[2], Q3 = pp[3];             \
    float pz = 0.f;                                                    \
    if (UPD) pz = p_lds[RBUF][0];                                      \
    HR = hb[(TR) * Ll + wcol];                                         \
    MR = mk_lds[(TR)];                                                 \
    v2f q00 = {Q0.x,Q0.y}, q01 = {Q0.z,Q0.w};                          \
    v2f q10 = {Q1.x,Q1.y}, q11 = {Q1.z,Q1.w};                          \
    v2f q20 = {Q2.x,Q2.y}, q21 = {Q2.z,Q2.w};                          \
    v2f A0 = {0.f,0.f}, A1 = {0.f,0.f}, A2 = {0.f,0.f}, A3 = {0.f,0.f};\
    v2f q30 = {Q3.x,Q3.y}, q31 = {Q3.z,Q3.w};                          \
    A0 = q00*EA0 + A0; A0 = q01*EA1 + A0; A0 = q10*EA2 + A0;           \
    A0 = q11*EA3 + A0; A0 = q20*EA4 + A0; A0 = q21*EA5 + A0;           \
    A0 = q30*EA6 + A0; A0 = q31*EA7 + A0;                              \
    A1 = q00*EB0 + A1; A1 = q01*EB1 + A1; A1 = q10*EB2 + A1;           \
    A1 = q11*EB3 + A1; A1 = q20*EB4 + A1; A1 = q21*EB5 + A1;           \
    A1 = q30*EB6 + A1; A1 = q31*EB7 + A1;                              \
    A2 = q00*EC0 + A2; A2 = q01*EC1 + A2; A2 = q10*EC2 + A2;           \
    A2 = q11*EC3 + A2; A2 = q20*EC4 + A2; A2 = q21*EC5 + A2;           \
    A2 = q30*EC6 + A2; A2 = q31*EC7 + A2;                              \
    A3 = q00*ED0 + A3; A3 = q01*ED1 + A3; A3 = q10*ED2 + A3;           \
    A3 = q11*ED3 + A3; A3 = q20*ED4 + A3; A3 = q21*ED5 + A3;           \
    A3 = q30*ED6 + A3; A3 = q31*ED7 + A3;                              \
    float a0 = A0.x + A0.y, a1 = A1.x + A1.y;                          \
    float a2 = A2.x + A2.y, a3 = A3.x + A3.y;                          \
    a0 += DPPA(a0,0xB1); a0 += DPPA(a0,0x4E); a0 += DPPA(a0,0x141);    \
    a1 += DPPA(a1,0xB1); a1 += DPPA(a1,0x4E); a1 += DPPA(a1,0x141);    \
    a2 += DPPA(a2,0xB1); a2 += DPPA(a2,0x4E); a2 += DPPA(a2,0x141);    \
    a3 += DPPA(a3,0xB1); a3 += DPPA(a3,0x4E); a3 += DPPA(a3,0x141);    \
    float s01 = (isl & 1) ? a1 : a0;                                   \
    float s23 = (isl & 1) ? a3 : a2;                                   \
    float acc = (isl & 2) ? s23 : s01;                                 \
    float c1 = EXc, c0 = pw * OMc;                                     \
    if (UPD) { float ed = __fdividef(1.12535175e-7f, pz);              \
               c1 *= ed; c0 *= ed; S += __logf(pz) + 16.0f; }          \
    float pn = fmaf(acc, c1, c0);                                      \
    if (writer) p_lds[(RBUF) ^ 1][waddr] = pn;                         \
    EXn = __expf(HN) * MN; OMn = 1.f - MN;                             \
    pw = pn;                                                           \
    asm volatile("s_waitcnt lgkmcnt(0)\n\ts_barrier" ::: "memory");    \
}

    // pre-loop bodies: t = 1, 2, 3 (regular; S unchanged)
    BODY(0, 0, ex1, om1, h2, m2, ex2, om2, h1, m1, 5)
    BODY(1, 0, ex2, om2, h3, m3, ex3, om3, h2, m2, 6)
    BODY(0, 0, ex3, om3, h0, m0, ex0, om0, h3, m3, 7)

    // main loop: k = 1..254, t = 4k (update), 4k+1, 4k+2, 4k+3.
    // TR = t+4 <= 1023 throughout -> no clamp arithmetic in the hot loop.
    for (int k = 1; k < 255; ++k) {
        int t4 = k << 2;
        BODY(1, 1, ex0, om0, h1, m1, ex1, om1, h0, m0, t4 + 4)
        BODY(0, 0, ex1, om1, h2, m2, ex2, om2, h1, m1, t4 + 5)
        BODY(1, 0, ex2, om2, h3, m3, ex3, om3, h2, m2, t4 + 6)
        BODY(0, 0, ex3, om3, h0, m0, ex0, om0, h3, m3, t4 + 7)
    }
    // tail k = 255: t = 1020..1023; refills are dummies (never consumed)
    BODY(1, 1, ex0, om0, h1, m1, ex1, om1, h0, m0, Tt - 1)
    BODY(0, 0, ex1, om1, h2, m2, ex2, om2, h1, m1, Tt - 1)
    BODY(1, 0, ex2, om2, h3, m3, ex3, om3, h2, m2, Tt - 1)
    BODY(0, 0, ex3, om3, h0, m0, ex0, om0, h3, m3, Tt - 1)
#undef BODY
#undef DPPA

    // ---- final logsumexp: score_j = log(p_T[j]) + S ----
    float v = __logf(pw) + S + end_trans[wcol];
    float mval = writer ? v : -1e30f;
    #pragma unroll
    for (int off = 32; off; off >>= 1) mval = fmaxf(mval, __shfl_xor(mval, off, 64));
    if (lane == 0) redm[wave] = mval;
    __syncthreads();
    float M = fmaxf(fmaxf(redm[0], redm[1]), fmaxf(redm[2], redm[3]));
    float e = writer ? __expf(v - M) : 0.f;
    #pragma unroll
    for (int off = 32; off; off >>= 1) e += __shfl_xor(e, off, 64);
    if (lane == 0) reds[wave] = e;
    __syncthreads();
    if (tid == 0) {
        float den = M + __logf(reds[0] + reds[1] + reds[2] + reds[3]);
        out[b] = num_in[b] - den;
    }
}

extern "C" void kernel_launch(void* const* d_in, const int* in_sizes, int n_in,
                              void* d_out, int out_size, void* d_ws, size_t ws_size,
                              hipStream_t stream) {
    const float* h           = (const float*)d_in[0];
    const int*   labels      = (const int*)d_in[1];
    const float* mask        = (const float*)d_in[2];
    const float* trans       = (const float*)d_in[3];
    const float* start_trans = (const float*)d_in[4];
    const float* end_trans   = (const float*)d_in[5];
    float* out    = (float*)d_out;
    float* num_ws = (float*)d_ws;                 // [0, 256)         num results
    float* expT   = (float*)d_ws + 256;           // [256, 256+16384) exp(trans)^T

    crf_expT_kernel<<<(Ll * Ll + 255) / 256, 256, 0, stream>>>(trans, expT);
    crf_num_kernel<<<Bb, 256, 0, stream>>>(h, labels, mask, trans, start_trans, end_trans, num_ws);
    crf_den_kernel<<<Bb, 256, 0, stream>>>(h, mask, expT, start_trans, end_trans, num_ws, out);
}

// Round 11
// 256.142 us; speedup vs baseline: 2.3523x; 1.0264x over previous
//
#include <hip/hip_runtime.h>
#include <math.h>

#define Bb 256
#define Tt 1024
#define Ll 128

typedef float v2f __attribute__((ext_vector_type(2)));

// ---------------- exp(trans) transpose precompute ----------------
// expT[j*128 + i] = exp(trans[i*128 + j])
__global__ __launch_bounds__(256) void crf_expT_kernel(
    const float* __restrict__ trans, float* __restrict__ expT)
{
    int idx = blockIdx.x * 256 + threadIdx.x;   // idx = j*128 + i
    if (idx < Ll * Ll) {
        int jj = idx >> 7;
        int ii = idx & (Ll - 1);
        expT[idx] = __expf(trans[ii * Ll + jj]);
    }
}

// ---------------- numerator kernel ----------------
__global__ __launch_bounds__(256) void crf_num_kernel(
    const float* __restrict__ h, const int* __restrict__ labels,
    const float* __restrict__ mask, const float* __restrict__ trans,
    const float* __restrict__ start_trans, const float* __restrict__ end_trans,
    float* __restrict__ num_out)
{
    const int b = blockIdx.x;
    const int tid = threadIdx.x;
    const int* lab = labels + b * Tt;
    const float* mk = mask + b * Tt;
    const float* hb = h + (size_t)b * Tt * Ll;

    float acc = 0.f;
    float msum = 0.f;
    for (int t = tid; t < Tt; t += 256) {
        int lt = lab[t];
        float mt = mk[t];
        msum += mt;
        if (t < Tt - 1) {
            int lt1 = lab[t + 1];
            acc += hb[t * Ll + lt] * mt + trans[lt * Ll + lt1] * mk[t + 1];
        }
    }
    for (int off = 32; off; off >>= 1) {
        acc  += __shfl_down(acc, off, 64);
        msum += __shfl_down(msum, off, 64);
    }
    __shared__ float racc[4], rmsum[4];
    const int wave = tid >> 6;
    if ((tid & 63) == 0) { racc[wave] = acc; rmsum[wave] = msum; }
    __syncthreads();
    if (tid == 0) {
        float a = racc[0] + racc[1] + racc[2] + racc[3];
        float m = rmsum[0] + rmsum[1] + rmsum[2] + rmsum[3];
        int last_idx = (int)(m + 0.5f) - 1;
        if (last_idx < 0) last_idx = 0;
        if (last_idx > Tt - 1) last_idx = Tt - 1;
        int last_lab = lab[last_idx];
        float num = a + start_trans[lab[0]];
        num += hb[(Tt - 1) * Ll + last_lab] * mk[Tt - 1];
        num += end_trans[last_lab];
        num_out[b] = num;
    }
}

// ---------------- denominator (forward scan) kernel ----------------
// R10 structure (4 waves, 4 cols x 16 i per thread, DPP butterfly, padded p,
// slot-refill x4 unroll, shift update every 4th step, mask staged in LDS),
// with two instruction-level fixes:
//  * GUARANTEED v_pk_fma_f32: R10's v2f ext-vector arithmetic appears not to
//    have contracted (VALUBusy implies ~136 instr/body vs ~70 structural).
//    The 64-MAC dot product is now 32 inline-asm VOP3P pk-fmas.
//  * m201-pattern barrier: sched_barrier(0); s_waitcnt lgkmcnt(0);
//    s_barrier builtin; sched_barrier(0). No "memory" clobber -> no IR-level
//    conservatism; sched_barrier pins LDS op order (guide rule #18); counted
//    vmcnt for the h-refills stays in flight (verified m201/m218 behavior).
__global__ __launch_bounds__(256)
__attribute__((amdgpu_waves_per_eu(1, 1)))
void crf_den_kernel(
    const float* __restrict__ h, const float* __restrict__ mask,
    const float* __restrict__ expT, const float* __restrict__ start_trans,
    const float* __restrict__ end_trans, const float* __restrict__ num_in,
    float* __restrict__ out)
{
    __shared__ float p_lds[2][160];      // padded: addr(i) = i + (i>>4)*4
    __shared__ float mk_lds[Tt];         // staged mask row (4KB)
    __shared__ float redm[4], reds[4];

    const int b = blockIdx.x;
    const int tid = threadIdx.x;
    const int wave = tid >> 6;
    const int lane = tid & 63;
    const int jgrp = lane >> 3;                    // 8 column-groups per wave
    const int isl  = lane & 7;                     // i-slice 0..7 (16 i each)
    const int jbase = (wave << 5) + (jgrp << 2);   // 4 columns per thread
    const int wcol  = jbase + (isl & 3);           // column this lane writes
    const bool writer = (isl < 4);
    const int waddr = wcol + ((wcol >> 4) << 2);

    const float* hb = h + (size_t)b * Tt * Ll;
    const float* mk = mask + b * Tt;

    // stage mask row into LDS, vectorized (256 threads x float4 = 1024)
    ((float4*)mk_lds)[tid] = ((const float4*)mk)[tid];

    // E fragment: cols jbase+0..3, i in [isl*16, isl*16+16) -> 32 v2f regs
    const v2f* EAp = (const v2f*)(expT + (jbase + 0) * Ll + (isl << 4));
    const v2f* EBp = (const v2f*)(expT + (jbase + 1) * Ll + (isl << 4));
    const v2f* ECp = (const v2f*)(expT + (jbase + 2) * Ll + (isl << 4));
    const v2f* EDp = (const v2f*)(expT + (jbase + 3) * Ll + (isl << 4));
    v2f EA0=EAp[0],EA1=EAp[1],EA2=EAp[2],EA3=EAp[3],EA4=EAp[4],EA5=EAp[5],EA6=EAp[6],EA7=EAp[7];
    v2f EB0=EBp[0],EB1=EBp[1],EB2=EBp[2],EB3=EBp[3],EB4=EBp[4],EB5=EBp[5],EB6=EBp[6],EB7=EBp[7];
    v2f EC0=ECp[0],EC1=ECp[1],EC2=ECp[2],EC3=ECp[3],EC4=ECp[4],EC5=ECp[5],EC6=ECp[6],EC7=ECp[7];
    v2f ED0=EDp[0],ED1=EDp[1],ED2=EDp[2],ED3=EDp[3],ED4=EDp[4],ED5=EDp[5],ED6=EDp[6],ED7=EDp[7];

    // bootstrap t = 0: shift S0 = score_0[0] + 16, computed uniformly
    float S = start_trans[0] + hb[0] + 16.0f;
    float score0 = start_trans[wcol] + hb[wcol];
    float pw = __expf(score0 - S);
    if (writer) p_lds[0][waddr] = pw;

    // h/mask slots (slot r holds data for time t with t&3 == r)
    float h1 = hb[1 * Ll + wcol], m1 = mk[1];
    float h2 = hb[2 * Ll + wcol], m2 = mk[2];
    float h3 = hb[3 * Ll + wcol], m3 = mk[3];
    float h0 = hb[4 * Ll + wcol], m0 = mk[4];
    __syncthreads();

    float ex1 = __expf(h1) * m1, om1 = 1.f - m1;
    float ex0, om0, ex2, om2, ex3, om3;

#define DPPA(x, ctrl) __int_as_float(__builtin_amdgcn_update_dpp( \
        0, __float_as_int(x), ctrl, 0xF, 0xF, true))

    // guaranteed packed fp32 fma: A = Q*E + A (elementwise on 2 lanes)
#define PKFMA(A, Q, E) asm("v_pk_fma_f32 %0, %1, %2, %0" : "+v"(A) : "v"(Q), "v"(E));

    // BODY: one scan step. RBUF = buffer read (write RBUF^1). UPD = shift
    // update step. EXc/OMc = this step's coeffs (prepared last body).
    // EXn/OMn prepared here from slot (HN,MN) for the NEXT body.
    // (HR,MR) refilled with time TR (consumed 3 bodies later; h from global
    // [vmcnt, never drained], mask from LDS broadcast [lgkm, same-step ok]).
#define BODY(RBUF, UPD, EXc, OMc, HN, MN, EXn, OMn, HR, MR, TR) {      \
    const float4* pp = (const float4*)(&p_lds[RBUF][isl * 20]);        \
    float4 Q0 = pp[0], Q1 = pp[1], Q2 = pp[2], Q3 = pp[3];             \
    float pz = 0.f;                                                    \
    if (UPD) pz = p_lds[RBUF][0];                                      \
    HR = hb[(TR) * Ll + wcol];                                         \
    MR = mk_lds[(TR)];                                                 \
    v2f q00 = {Q0.x,Q0.y}, q01 = {Q0.z,Q0.w};                          \
    v2f q10 = {Q1.x,Q1.y}, q11 = {Q1.z,Q1.w};                          \
    v2f q20 = {Q2.x,Q2.y}, q21 = {Q2.z,Q2.w};                          \
    v2f q30 = {Q3.x,Q3.y}, q31 = {Q3.z,Q3.w};                          \
    v2f A0 = {0.f,0.f}, A1 = {0.f,0.f}, A2 = {0.f,0.f}, A3 = {0.f,0.f};\
    PKFMA(A0, q00, EA0) PKFMA(A0, q01, EA1) PKFMA(A0, q10, EA2)        \
    PKFMA(A0, q11, EA3) PKFMA(A0, q20, EA4) PKFMA(A0, q21, EA5)        \
    PKFMA(A0, q30, EA6) PKFMA(A0, q31, EA7)                            \
    PKFMA(A1, q00, EB0) PKFMA(A1, q01, EB1) PKFMA(A1, q10, EB2)        \
    PKFMA(A1, q11, EB3) PKFMA(A1, q20, EB4) PKFMA(A1, q21, EB5)        \
    PKFMA(A1, q30, EB6) PKFMA(A1, q31, EB7)                            \
    PKFMA(A2, q00, EC0) PKFMA(A2, q01, EC1) PKFMA(A2, q10, EC2)        \
    PKFMA(A2, q11, EC3) PKFMA(A2, q20, EC4) PKFMA(A2, q21, EC5)        \
    PKFMA(A2, q30, EC6) PKFMA(A2, q31, EC7)                            \
    PKFMA(A3, q00, ED0) PKFMA(A3, q01, ED1) PKFMA(A3, q10, ED2)        \
    PKFMA(A3, q11, ED3) PKFMA(A3, q20, ED4) PKFMA(A3, q21, ED5)        \
    PKFMA(A3, q30, ED6) PKFMA(A3, q31, ED7)                            \
    float a0 = A0.x + A0.y, a1 = A1.x + A1.y;                          \
    float a2 = A2.x + A2.y, a3 = A3.x + A3.y;                          \
    a0 += DPPA(a0,0xB1); a0 += DPPA(a0,0x4E); a0 += DPPA(a0,0x141);    \
    a1 += DPPA(a1,0xB1); a1 += DPPA(a1,0x4E); a1 += DPPA(a1,0x141);    \
    a2 += DPPA(a2,0xB1); a2 += DPPA(a2,0x4E); a2 += DPPA(a2,0x141);    \
    a3 += DPPA(a3,0xB1); a3 += DPPA(a3,0x4E); a3 += DPPA(a3,0x141);    \
    float s01 = (isl & 1) ? a1 : a0;                                   \
    float s23 = (isl & 1) ? a3 : a2;                                   \
    float acc = (isl & 2) ? s23 : s01;                                 \
    float c1 = EXc, c0 = pw * OMc;                                     \
    if (UPD) { float ed = __fdividef(1.12535175e-7f, pz);              \
               c1 *= ed; c0 *= ed; S += __logf(pz) + 16.0f; }          \
    float pn = fmaf(acc, c1, c0);                                      \
    if (writer) p_lds[(RBUF) ^ 1][waddr] = pn;                         \
    EXn = __expf(HN) * MN; OMn = 1.f - MN;                             \
    pw = pn;                                                           \
    __builtin_amdgcn_sched_barrier(0);                                 \
    asm volatile("s_waitcnt lgkmcnt(0)");                              \
    __builtin_amdgcn_s_barrier();                                      \
    __builtin_amdgcn_sched_barrier(0);                                 \
}

    // pre-loop bodies: t = 1, 2, 3 (regular; S unchanged)
    BODY(0, 0, ex1, om1, h2, m2, ex2, om2, h1, m1, 5)
    BODY(1, 0, ex2, om2, h3, m3, ex3, om3, h2, m2, 6)
    BODY(0, 0, ex3, om3, h0, m0, ex0, om0, h3, m3, 7)

    // main loop: k = 1..254, t = 4k (update), 4k+1, 4k+2, 4k+3.
    // TR = t+4 <= 1023 throughout -> no clamp arithmetic in the hot loop.
    for (int k = 1; k < 255; ++k) {
        int t4 = k << 2;
        BODY(1, 1, ex0, om0, h1, m1, ex1, om1, h0, m0, t4 + 4)
        BODY(0, 0, ex1, om1, h2, m2, ex2, om2, h1, m1, t4 + 5)
        BODY(1, 0, ex2, om2, h3, m3, ex3, om3, h2, m2, t4 + 6)
        BODY(0, 0, ex3, om3, h0, m0, ex0, om0, h3, m3, t4 + 7)
    }
    // tail k = 255: t = 1020..1023; refills are dummies (never consumed)
    BODY(1, 1, ex0, om0, h1, m1, ex1, om1, h0, m0, Tt - 1)
    BODY(0, 0, ex1, om1, h2, m2, ex2, om2, h1, m1, Tt - 1)
    BODY(1, 0, ex2, om2, h3, m3, ex3, om3, h2, m2, Tt - 1)
    BODY(0, 0, ex3, om3, h0, m0, ex0, om0, h3, m3, Tt - 1)
#undef BODY
#undef PKFMA
#undef DPPA

    // ---- final logsumexp: score_j = log(p_T[j]) + S ----
    float v = __logf(pw) + S + end_trans[wcol];
    float mval = writer ? v : -1e30f;
    #pragma unroll
    for (int off = 32; off; off >>= 1) mval = fmaxf(mval, __shfl_xor(mval, off, 64));
    if (lane == 0) redm[wave] = mval;
    __syncthreads();
    float M = fmaxf(fmaxf(redm[0], redm[1]), fmaxf(redm[2], redm[3]));
    float e = writer ? __expf(v - M) : 0.f;
    #pragma unroll
    for (int off = 32; off; off >>= 1) e += __shfl_xor(e, off, 64);
    if (lane == 0) reds[wave] = e;
    __syncthreads();
    if (tid == 0) {
        float den = M + __logf(reds[0] + reds[1] + reds[2] + reds[3]);
        out[b] = num_in[b] - den;
    }
}

extern "C" void kernel_launch(void* const* d_in, const int* in_sizes, int n_in,
                              void* d_out, int out_size, void* d_ws, size_t ws_size,
                              hipStream_t stream) {
    const float* h           = (const float*)d_in[0];
    const int*   labels      = (const int*)d_in[1];
    const float* mask        = (const float*)d_in[2];
    const float* trans       = (const float*)d_in[3];
    const float* start_trans = (const float*)d_in[4];
    const float* end_trans   = (const float*)d_in[5];
    float* out    = (float*)d_out;
    float* num_ws = (float*)d_ws;                 // [0, 256)         num results
    float* expT   = (float*)d_ws + 256;           // [256, 256+16384) exp(trans)^T

    crf_expT_kernel<<<(Ll * Ll + 255) / 256, 256, 0, stream>>>(trans, expT);
    crf_num_kernel<<<Bb, 256, 0, stream>>>(h, labels, mask, trans, start_trans, end_trans, num_ws);
    crf_den_kernel<<<Bb, 256, 0, stream>>>(h, mask, expT, start_trans, end_trans, num_ws, out);
}